// Round 11
// baseline (622.594 us; speedup 1.0000x reference)
//
#include <hip/hip_runtime.h>
#include <stdint.h>

#define B_ROWS 8192
#define D_EMB  768
#define D_HID  24576
#define CAP    512
#define TAU    2.40f
#define DELTA  0.03f
#define BANDCAP 64
#define LSLOT  12

typedef float f32x4  __attribute__((ext_vector_type(4)));
typedef short s16x8  __attribute__((ext_vector_type(8)));

#define GPTR(p) ((const __attribute__((address_space(1))) void*)(const void*)(p))
#define LPTR(p) ((__attribute__((address_space(3))) void*)(void*)(p))

__device__ __forceinline__ unsigned short f2bf_rne(float f) {
    uint32_t u = __builtin_bit_cast(uint32_t, f);
    u += 0x7fffu + ((u >> 16) & 1u);
    return (unsigned short)(u >> 16);
}
__device__ __forceinline__ float bf2f(unsigned short h) {
    uint32_t u = ((uint32_t)h) << 16;
    return __builtin_bit_cast(float, u);
}

// ---------------- fp32 -> bf16 (RNE) bulk convert ---------------------------
__global__ __launch_bounds__(256) void k_cvt(const float* __restrict__ src,
                                             unsigned short* __restrict__ dst, int n4)
{
    int i = blockIdx.x * 256 + threadIdx.x;
    const int stride = gridDim.x * 256;
    for (; i < n4; i += stride) {
        float4 v = ((const float4*)src)[i];
        ushort4 o;
        o.x = f2bf_rne(v.x); o.y = f2bf_rne(v.y);
        o.z = f2bf_rne(v.z); o.w = f2bf_rne(v.w);
        ((ushort4*)dst)[i] = o;
    }
}

// ------------- transpose W_down [768][24576] -> Wdt bf16 [24576][768] -------
__global__ __launch_bounds__(256) void k_transpose_bf(const float* __restrict__ W,
                                                      unsigned short* __restrict__ WT)
{
    __shared__ float tile[32][33];
    const int bx = blockIdx.x * 32;   // along D_HID
    const int by = blockIdx.y * 32;   // along D_EMB
    const int tx = threadIdx.x, ty = threadIdx.y;
    #pragma unroll
    for (int r = ty; r < 32; r += 8)
        tile[r][tx] = W[(size_t)(by + r) * D_HID + bx + tx];
    __syncthreads();
    #pragma unroll
    for (int r = ty; r < 32; r += 8)
        WT[(size_t)(bx + r) * D_EMB + by + tx] = f2bf_rne(tile[tx][r]);
}

// ---- phase 1: bf16 MFMA GEMM, 128x128, ring-3 + counted vmcnt + raw bar ----
// Abf = embs bf16 [8192][768], Bbf = W_up bf16 [24576][768]; C = A*B^T
// LDS: 3 slot-pairs (A,B 128x32 bf16 each) = 48 KB; slot = tile % 3.
// Row = 64 B = 4 chunks of 16 B; physical chunk s of row r holds global
// k-chunk s ^ ((r>>1)&3) (pre-swizzled source, linear gload_lds dest;
// measured SQ_LDS_BANK_CONFLICT ~ 0 in the K-loop).
// Per iter t: s_waitcnt vmcnt(4)  -> retires EXACTLY tile t's 4 loads
//             (issued at iter t-2, ~2 iters of latency cover);
//             s_barrier (after-wait: all waves' tile-t loads visible);
//             stage(t+2) into slot (t+2)%3 == (t-1)%3 (WAR-safe: the barrier
//             proves all iter-(t-1) reads retired);
//             ds_read slot t%3; 16 MFMA.  NO vmcnt(0) drain in the loop.
// Epilogue (round-8/10 verified): LDS-aggregated emission, unioned onto As.
__global__ __launch_bounds__(256) void k_gemm_cand(
    const unsigned short* __restrict__ Abf, const unsigned short* __restrict__ Bbf,
    const float* __restrict__ bias, int* __restrict__ counts,
    uint2* __restrict__ cand8)
{
    __shared__ __align__(16) unsigned short As[3][128 * 32];   // 24 KB
    __shared__ __align__(16) unsigned short Bs[3][128 * 32];   // 24 KB
    // epilogue views aliased onto As (24 KB >= 13 KB needed)
    int*   lc    = (int*)&As[0][0];                 // [128]
    int*   lbase = lc + 128;                        // [128]
    uint2* lcand = (uint2*)(lbase + 128);           // [128][LSLOT] = 12 KB

    const int tid  = threadIdx.x;
    const int bm   = blockIdx.x * 128;
    const int bn   = blockIdx.y * 128;
    const int lane = tid & 63;
    const int wid  = tid >> 6;
    const int wr   = (wid >> 1) * 64;
    const int wc   = (wid & 1) * 64;

    // staging: 4 threads per row, 16B each; 2 issues cover 128 rows
    const int srow  = tid >> 2;                      // 0..63
    const int sslot = tid & 3;                       // 16B slot
    const int kc    = sslot ^ ((srow >> 1) & 3);     // swizzled global k-chunk

    const unsigned short* ga0 = Abf + (size_t)(bm + srow) * D_EMB + kc * 8;
    const unsigned short* gb0 = Bbf + (size_t)(bn + srow) * D_EMB + kc * 8;
    const int ldst = srow * 32 + sslot * 8;          // ushort index, linear

    auto stage = [&](int sl, int t) {                // 4 x global_load_lds(16B)
        const int k0 = t * 32;
        __builtin_amdgcn_global_load_lds(GPTR(ga0 + k0),
                                         LPTR(&As[sl][ldst]), 16, 0, 0);
        __builtin_amdgcn_global_load_lds(GPTR(ga0 + (size_t)64 * D_EMB + k0),
                                         LPTR(&As[sl][ldst + 64 * 32]), 16, 0, 0);
        __builtin_amdgcn_global_load_lds(GPTR(gb0 + k0),
                                         LPTR(&Bs[sl][ldst]), 16, 0, 0);
        __builtin_amdgcn_global_load_lds(GPTR(gb0 + (size_t)64 * D_EMB + k0),
                                         LPTR(&Bs[sl][ldst + 64 * 32]), 16, 0, 0);
    };

    f32x4 acc[4][4] = {};

    const int l15 = lane & 15, hi4 = lane >> 4;
    const int sw  = hi4 ^ ((l15 >> 1) & 3);          // read-side swizzle

    auto body = [&](int sl) {
        s16x8 av[4], bv[4];
        #pragma unroll
        for (int i = 0; i < 4; ++i) {
            av[i] = *(const s16x8*)(&As[sl][(wr + i * 16 + l15) * 32 + sw * 8]);
            bv[i] = *(const s16x8*)(&Bs[sl][(wc + i * 16 + l15) * 32 + sw * 8]);
        }
        __builtin_amdgcn_s_setprio(1);
        #pragma unroll
        for (int i = 0; i < 4; ++i)
            #pragma unroll
            for (int j = 0; j < 4; ++j)
                acc[i][j] = __builtin_amdgcn_mfma_f32_16x16x32_bf16(av[i], bv[j], acc[i][j], 0, 0, 0);
        __builtin_amdgcn_s_setprio(0);
    };

#define VMW(N) asm volatile("s_waitcnt vmcnt(" #N ")" ::: "memory")
#define BAR()  __builtin_amdgcn_s_barrier()

    // prologue: tiles 0,1 -> slots 0,1 (8 loads in flight)
    stage(0, 0); stage(1, 1);

    // iters 0..21: uniform {VMW(4); BAR; stage(t+2); body(t%3)}
    #pragma unroll 1
    for (int t = 0; t < 21; t += 3) {
        VMW(4); BAR(); stage((t + 2) % 3, t + 2); body(t % 3);
        VMW(4); BAR(); stage((t + 3) % 3, t + 3); body((t + 1) % 3);
        VMW(4); BAR(); stage((t + 4) % 3, t + 4); body((t + 2) % 3);
    }
    // t=21: last stage (tile 23)
    VMW(4); BAR(); stage(2, 23); body(0);
    // t=22: no stage
    VMW(4); BAR(); body(1);
    // t=23: full drain
    VMW(0); BAR(); body(2);

#undef VMW
#undef BAR

    // staging buffers now dead; re-init aliased epilogue state
    __syncthreads();
    if (tid < 128) lc[tid] = 0;
    __syncthreads();

    // epilogue v2: C/D mapping col = lane&15, row = (lane>>4)*4 + reg  [m89]
    // pass 1: hits -> per-row LDS lists (LDS atomics)
    #pragma unroll
    for (int i = 0; i < 4; ++i) {
        const int lr0 = wr + i * 16 + hi4 * 4;       // local row base 0..127
        #pragma unroll
        for (int j = 0; j < 4; ++j) {
            const int c = bn + wc + j * 16 + l15;
            const float bb = bias[c];
            #pragma unroll
            for (int r = 0; r < 4; ++r) {
                const float z = acc[i][j][r] + bb;
                if (z > TAU) {
                    const int lr = lr0 + r;
                    const int p = atomicAdd(&lc[lr], 1);
                    if (p < LSLOT) {
                        uint2 e; e.x = (uint32_t)c; e.y = __builtin_bit_cast(uint32_t, z);
                        lcand[lr * LSLOT + p] = e;
                    }
                }
            }
        }
    }
    __syncthreads();
    // pass 2: one batched global atomic per nonzero row (parallel round-trips)
    if (tid < 128) {
        int n = lc[tid]; n = n > LSLOT ? LSLOT : n;
        lc[tid] = n;
        lbase[tid] = n ? atomicAdd(&counts[bm + tid], n) : 0;
    }
    __syncthreads();
    // pass 3: coalesced copy-out
    for (int s = tid; s < 128 * LSLOT; s += 256) {
        const int lr = s / LSLOT, k = s % LSLOT;
        if (k < lc[lr]) {
            const int pos = lbase[lr] + k;
            if (pos < CAP) cand8[(size_t)(bm + lr) * CAP + pos] = lcand[lr * LSLOT + k];
        }
    }
}

// -------- phase 2+3: two-tier select (f64 only near boundary) + down-proj ---
__global__ __launch_bounds__(256) void k_select_project(
    const float* __restrict__ embs, const float* __restrict__ W_up,
    const float* __restrict__ b_up, const unsigned short* __restrict__ Wdt,
    const int* __restrict__ counts, const uint2* __restrict__ cand8,
    float* __restrict__ out)
{
    const int row = blockIdx.x;
    const int t = threadIdx.x, lane = t & 63, wid = t >> 6;

    __shared__ __align__(16) float e_sh[D_EMB];
    __shared__ float  zv[CAP];
    __shared__ int    idx[CAP];
    __shared__ float  red[256];
    __shared__ double redd[128];
    __shared__ int    bidx[BANDCAP];
    __shared__ double bex[BANDCAP];
    __shared__ float  selv[40];
    __shared__ int    seli[40];
    __shared__ int    nband, nsel;

    for (int k = t; k < D_EMB; k += 256) e_sh[k] = embs[(size_t)row * D_EMB + k];
    int n = counts[row]; if (n > CAP) n = CAP;
    for (int c = t; c < n; c += 256) {
        uint2 e = cand8[(size_t)row * CAP + c];
        idx[c] = (int)e.x;
        zv[c]  = __builtin_bit_cast(float, e.y);
    }
    if (t == 0) { nband = 0; nsel = 0; }
    __syncthreads();

    // approximate kth = 32nd largest of z~ (rank count, ties-aware)
    float best = -1e30f;
    for (int c = t; c < n; c += 256) {
        const float v = zv[c]; int ge = 0;
        for (int j = 0; j < n; ++j) ge += (zv[j] >= v) ? 1 : 0;
        if (ge >= 32 && v > best) best = v;
    }
    red[t] = best; __syncthreads();
    for (int st = 128; st > 0; st >>= 1) {
        if (t < st) { const float o = red[t + st]; if (o > red[t]) red[t] = o; }
        __syncthreads();
    }
    const float kthA = red[0];

    // classify: confident-in (a = z~) / band (exact rescore) / out
    for (int c = t; c < n; c += 256) {
        const float v = zv[c];
        if (v > kthA + DELTA) {
            const int p = atomicAdd(&nsel, 1);
            if (p < 40) { selv[p] = v; seli[p] = idx[c]; }
        } else if (v >= kthA - DELTA) {
            const int p = atomicAdd(&nband, 1);
            if (p < BANDCAP) bidx[p] = idx[c];
        }
    }
    __syncthreads();
    const int nc = nsel < 40 ? nsel : 40;
    const int nb = nband < BANDCAP ? nband : BANDCAP;
    const int r  = 32 - nc;   // >= 1

    // exact f64 rescore of band candidates (one wave each)
    for (int c = wid; c < nb; c += 4) {
        const int h = bidx[c];
        const float* wrow = W_up + (size_t)h * D_EMB;
        double s = 0.0;
        #pragma unroll
        for (int j = 0; j < 3; ++j) {
            f32x4 wv = *(const f32x4*)(wrow + lane * 4 + j * 256);
            f32x4 ev = *(const f32x4*)(&e_sh[lane * 4 + j * 256]);
            s += (double)ev[0] * wv[0] + (double)ev[1] * wv[1]
               + (double)ev[2] * wv[2] + (double)ev[3] * wv[3];
        }
        #pragma unroll
        for (int o = 32; o > 0; o >>= 1) s += __shfl_down(s, o);
        if (lane == 0) {
            const double z = s + (double)b_up[h];
            bex[c] = z > 0.0 ? z : 0.0;
        }
    }
    __syncthreads();

    // K = r-th largest exact band value; select strictly above K
    if (t < 128) redd[t] = -1.0;
    __syncthreads();
    if (t < nb) {
        const double v = bex[t]; int ge = 0;
        for (int j = 0; j < nb; ++j) ge += (bex[j] >= v) ? 1 : 0;
        if (ge >= r) redd[t] = v;
    }
    __syncthreads();
    for (int st = 64; st > 0; st >>= 1) {
        if (t < st) { const double o = redd[t + st]; if (o > redd[t]) redd[t] = o; }
        __syncthreads();
    }
    const double K = redd[0];

    if (t < nb && bex[t] > K) {
        const int p = atomicAdd(&nsel, 1);
        if (p < 40) { selv[p] = (float)bex[t]; seli[p] = bidx[t]; }
    }
    __syncthreads();
    const int ns = nsel < 40 ? nsel : 40;

    // x_hat[row] = sum_sel a * Wdt[h] (bf16 rows, ushort2 coalesced)
    for (int p = t; p < D_EMB / 2; p += 256) {
        float a0 = 0.f, a1 = 0.f;
        for (int c = 0; c < ns; ++c) {
            const uint32_t w2 = *(const uint32_t*)(Wdt + (size_t)seli[c] * D_EMB + 2 * p);
            a0 += selv[c] * bf2f((unsigned short)(w2 & 0xffffu));
            a1 += selv[c] * bf2f((unsigned short)(w2 >> 16));
        }
        float2 o; o.x = a0; o.y = a1;
        *(float2*)(out + (size_t)row * D_EMB + 2 * p) = o;
    }
}

// ------------------------------- launcher ------------------------------------
extern "C" void kernel_launch(void* const* d_in, const int* in_sizes, int n_in,
                              void* d_out, int out_size, void* d_ws, size_t ws_size,
                              hipStream_t stream)
{
    (void)in_sizes; (void)n_in; (void)out_size; (void)ws_size;
    const float* embs   = (const float*)d_in[0];
    const float* W_up   = (const float*)d_in[1];
    const float* b_up   = (const float*)d_in[2];
    const float* W_down = (const float*)d_in[3];
    float* out = (float*)d_out;

    char* w = (char*)d_ws;
    int*   counts = (int*)w;                                     // 64 KB
    uint2* cand8  = (uint2*)(w + (64 << 10));                    // 33.55 MB
    char*  r2     = w + (64 << 10) + (size_t)B_ROWS * CAP * 8;
    unsigned short* Abf = (unsigned short*)r2;                   // 12.58 MB
    unsigned short* Bbf = (unsigned short*)(r2 + (size_t)B_ROWS * D_EMB * 2); // 37.75 MB
    unsigned short* Wdt = (unsigned short*)r2;                   // aliases Abf/Bbf (used after GEMM)

    hipMemsetAsync(counts, 0, B_ROWS * sizeof(int), stream);
    k_cvt<<<1024, 256, 0, stream>>>(embs, Abf, B_ROWS * D_EMB / 4);
    k_cvt<<<2048, 256, 0, stream>>>(W_up, Bbf, D_HID * D_EMB / 4);

    k_gemm_cand<<<dim3(B_ROWS / 128, D_HID / 128), 256, 0, stream>>>(Abf, Bbf, b_up, counts, cand8);

    k_transpose_bf<<<dim3(D_HID / 32, D_EMB / 32), dim3(32, 8), 0, stream>>>(W_down, Wdt);

    k_select_project<<<B_ROWS, 256, 0, stream>>>(embs, W_up, b_up, Wdt, counts, cand8, out);
}

// Round 12
// 575.479 us; speedup vs baseline: 1.0819x; 1.0819x over previous
//
#include <hip/hip_runtime.h>
#include <stdint.h>

#define B_ROWS 8192
#define D_EMB  768
#define D_HID  24576
#define CAP    512
#define TAU    2.40f
#define DELTA  0.03f
#define BANDCAP 64
#define LSLOT  20

typedef float f32x4  __attribute__((ext_vector_type(4)));
typedef short s16x8  __attribute__((ext_vector_type(8)));

#define GPTR(p) ((const __attribute__((address_space(1))) void*)(const void*)(p))
#define LPTR(p) ((__attribute__((address_space(3))) void*)(void*)(p))

__device__ __forceinline__ unsigned short f2bf_rne(float f) {
    uint32_t u = __builtin_bit_cast(uint32_t, f);
    u += 0x7fffu + ((u >> 16) & 1u);
    return (unsigned short)(u >> 16);
}
__device__ __forceinline__ float bf2f(unsigned short h) {
    uint32_t u = ((uint32_t)h) << 16;
    return __builtin_bit_cast(float, u);
}

// ---------------- fp32 -> bf16 (RNE) bulk convert ---------------------------
__global__ __launch_bounds__(256) void k_cvt(const float* __restrict__ src,
                                             unsigned short* __restrict__ dst, int n4)
{
    int i = blockIdx.x * 256 + threadIdx.x;
    const int stride = gridDim.x * 256;
    for (; i < n4; i += stride) {
        float4 v = ((const float4*)src)[i];
        ushort4 o;
        o.x = f2bf_rne(v.x); o.y = f2bf_rne(v.y);
        o.z = f2bf_rne(v.z); o.w = f2bf_rne(v.w);
        ((ushort4*)dst)[i] = o;
    }
}

// ------------- transpose W_down [768][24576] -> Wdt bf16 [24576][768] -------
__global__ __launch_bounds__(256) void k_transpose_bf(const float* __restrict__ W,
                                                      unsigned short* __restrict__ WT)
{
    __shared__ float tile[32][33];
    const int bx = blockIdx.x * 32;   // along D_HID
    const int by = blockIdx.y * 32;   // along D_EMB
    const int tx = threadIdx.x, ty = threadIdx.y;
    #pragma unroll
    for (int r = ty; r < 32; r += 8)
        tile[r][tx] = W[(size_t)(by + r) * D_HID + bx + tx];
    __syncthreads();
    #pragma unroll
    for (int r = ty; r < 32; r += 8)
        WT[(size_t)(bx + r) * D_EMB + by + tx] = f2bf_rne(tile[tx][r]);
}

// -- phase 1: bf16 MFMA GEMM, 128x256 block, 64x128 wave tile + compaction ---
// Abf = embs bf16 [8192][768], Bbf = W_up bf16 [24576][768]; C = A*B^T
// Wave tile 64x128: 12 ds_read_b128 per 32 MFMA (0.375 vs 0.5 at 64x64) —
// cuts the dominant pipe (LDS reads, 41% of cycles at r10) by 25%.
// K-loop = the PROVEN r8 structure (stage-ahead + __syncthreads, 0-conflict
// chunk swizzle: physical chunk s of row r holds global k-chunk s^((r>>1)&3),
// pre-swizzled source, linear gload_lds dest).
// Epilogue: LDS-aggregated emission (r8-verified), unioned onto Bs staging.
__global__ __launch_bounds__(256, 2) void k_gemm_cand(
    const unsigned short* __restrict__ Abf, const unsigned short* __restrict__ Bbf,
    const float* __restrict__ bias, int* __restrict__ counts,
    uint2* __restrict__ cand8)
{
    __shared__ __align__(16) unsigned short As[2][128 * 32];   // 16 KB
    __shared__ __align__(16) unsigned short Bs[2][256 * 32];   // 32 KB
    // epilogue views aliased onto Bs (32 KB >= 21 KB needed)
    int*   lc    = (int*)&Bs[0][0];                 // [128]
    int*   lbase = lc + 128;                        // [128]
    uint2* lcand = (uint2*)(lbase + 128);           // [128][LSLOT] = 20 KB

    const int tid  = threadIdx.x;
    const int bm   = blockIdx.x * 128;
    const int bn   = blockIdx.y * 256;
    const int lane = tid & 63;
    const int wid  = tid >> 6;
    const int wr   = (wid >> 1) * 64;    // wave row offset (2 row-halves)
    const int wc   = (wid & 1) * 128;    // wave col offset (2 col-halves)

    // staging: 4 threads per row, 16B each; A: 2 issues (128 rows), B: 4 (256)
    const int srow  = tid >> 2;                      // 0..63
    const int sslot = tid & 3;                       // 16B slot
    const int kc    = sslot ^ ((srow >> 1) & 3);     // swizzled global k-chunk

    const unsigned short* ga0 = Abf + (size_t)(bm + srow) * D_EMB + kc * 8;
    const unsigned short* gb0 = Bbf + (size_t)(bn + srow) * D_EMB + kc * 8;
    const int ldst = srow * 32 + sslot * 8;          // ushort index, linear

    auto stage = [&](int buf, int k0) {
        __builtin_amdgcn_global_load_lds(GPTR(ga0 + k0),
                                         LPTR(&As[buf][ldst]), 16, 0, 0);
        __builtin_amdgcn_global_load_lds(GPTR(ga0 + (size_t)64 * D_EMB + k0),
                                         LPTR(&As[buf][ldst + 64 * 32]), 16, 0, 0);
        #pragma unroll
        for (int p = 0; p < 4; ++p)
            __builtin_amdgcn_global_load_lds(GPTR(gb0 + (size_t)(64 * p) * D_EMB + k0),
                                             LPTR(&Bs[buf][ldst + p * 64 * 32]), 16, 0, 0);
    };

    f32x4 acc[4][8] = {};

    stage(0, 0);
    __syncthreads();

    const int l15 = lane & 15, hi4 = lane >> 4;
    const int sw  = hi4 ^ ((l15 >> 1) & 3);          // read-side swizzle

    #pragma unroll 1
    for (int ks = 0; ks < D_EMB / 32; ++ks) {
        const int buf = ks & 1;
        if (ks < D_EMB / 32 - 1) stage(buf ^ 1, (ks + 1) * 32);

        s16x8 av[4], bv[8];
        #pragma unroll
        for (int i = 0; i < 4; ++i)
            av[i] = *(const s16x8*)(&As[buf][(wr + i * 16 + l15) * 32 + sw * 8]);
        #pragma unroll
        for (int j = 0; j < 8; ++j)
            bv[j] = *(const s16x8*)(&Bs[buf][(wc + j * 16 + l15) * 32 + sw * 8]);
        #pragma unroll
        for (int i = 0; i < 4; ++i)
            #pragma unroll
            for (int j = 0; j < 8; ++j)
                acc[i][j] = __builtin_amdgcn_mfma_f32_16x16x32_bf16(av[i], bv[j], acc[i][j], 0, 0, 0);
        __syncthreads();
    }
    // staging buffers now dead; re-init aliased epilogue state
    if (tid < 128) lc[tid] = 0;
    __syncthreads();

    // epilogue: C/D mapping col = lane&15, row = (lane>>4)*4 + reg  [m89]
    // pass 1: hits -> per-row LDS lists (LDS atomics)
    #pragma unroll
    for (int i = 0; i < 4; ++i) {
        const int lr0 = wr + i * 16 + hi4 * 4;       // local row base 0..127
        #pragma unroll
        for (int j = 0; j < 8; ++j) {
            const int c = bn + wc + j * 16 + l15;
            const float bb = bias[c];
            #pragma unroll
            for (int r = 0; r < 4; ++r) {
                const float z = acc[i][j][r] + bb;
                if (z > TAU) {
                    const int lr = lr0 + r;
                    const int p = atomicAdd(&lc[lr], 1);
                    if (p < LSLOT) {
                        uint2 e; e.x = (uint32_t)c; e.y = __builtin_bit_cast(uint32_t, z);
                        lcand[lr * LSLOT + p] = e;
                    }
                }
            }
        }
    }
    __syncthreads();
    // pass 2: one batched global atomic per nonzero row (parallel round-trips)
    if (tid < 128) {
        int n = lc[tid]; n = n > LSLOT ? LSLOT : n;
        lc[tid] = n;
        lbase[tid] = n ? atomicAdd(&counts[bm + tid], n) : 0;
    }
    __syncthreads();
    // pass 3: coalesced copy-out
    for (int s = tid; s < 128 * LSLOT; s += 256) {
        const int lr = s / LSLOT, k = s % LSLOT;
        if (k < lc[lr]) {
            const int pos = lbase[lr] + k;
            if (pos < CAP) cand8[(size_t)(bm + lr) * CAP + pos] = lcand[lr * LSLOT + k];
        }
    }
}

// -------- phase 2+3: two-tier select (f64 only near boundary) + down-proj ---
__global__ __launch_bounds__(256) void k_select_project(
    const float* __restrict__ embs, const float* __restrict__ W_up,
    const float* __restrict__ b_up, const unsigned short* __restrict__ Wdt,
    const int* __restrict__ counts, const uint2* __restrict__ cand8,
    float* __restrict__ out)
{
    const int row = blockIdx.x;
    const int t = threadIdx.x, lane = t & 63, wid = t >> 6;

    __shared__ __align__(16) float e_sh[D_EMB];
    __shared__ float  zv[CAP];
    __shared__ int    idx[CAP];
    __shared__ float  red[256];
    __shared__ double redd[128];
    __shared__ int    bidx[BANDCAP];
    __shared__ double bex[BANDCAP];
    __shared__ float  selv[40];
    __shared__ int    seli[40];
    __shared__ int    nband, nsel;

    for (int k = t; k < D_EMB; k += 256) e_sh[k] = embs[(size_t)row * D_EMB + k];
    int n = counts[row]; if (n > CAP) n = CAP;
    for (int c = t; c < n; c += 256) {
        uint2 e = cand8[(size_t)row * CAP + c];
        idx[c] = (int)e.x;
        zv[c]  = __builtin_bit_cast(float, e.y);
    }
    if (t == 0) { nband = 0; nsel = 0; }
    __syncthreads();

    // approximate kth = 32nd largest of z~ (rank count, ties-aware)
    float best = -1e30f;
    for (int c = t; c < n; c += 256) {
        const float v = zv[c]; int ge = 0;
        for (int j = 0; j < n; ++j) ge += (zv[j] >= v) ? 1 : 0;
        if (ge >= 32 && v > best) best = v;
    }
    red[t] = best; __syncthreads();
    for (int st = 128; st > 0; st >>= 1) {
        if (t < st) { const float o = red[t + st]; if (o > red[t]) red[t] = o; }
        __syncthreads();
    }
    const float kthA = red[0];

    // classify: confident-in (a = z~) / band (exact rescore) / out
    for (int c = t; c < n; c += 256) {
        const float v = zv[c];
        if (v > kthA + DELTA) {
            const int p = atomicAdd(&nsel, 1);
            if (p < 40) { selv[p] = v; seli[p] = idx[c]; }
        } else if (v >= kthA - DELTA) {
            const int p = atomicAdd(&nband, 1);
            if (p < BANDCAP) bidx[p] = idx[c];
        }
    }
    __syncthreads();
    const int nc = nsel < 40 ? nsel : 40;
    const int nb = nband < BANDCAP ? nband : BANDCAP;
    const int r  = 32 - nc;   // >= 1

    // exact f64 rescore of band candidates (one wave each)
    for (int c = wid; c < nb; c += 4) {
        const int h = bidx[c];
        const float* wrow = W_up + (size_t)h * D_EMB;
        double s = 0.0;
        #pragma unroll
        for (int j = 0; j < 3; ++j) {
            f32x4 wv = *(const f32x4*)(wrow + lane * 4 + j * 256);
            f32x4 ev = *(const f32x4*)(&e_sh[lane * 4 + j * 256]);
            s += (double)ev[0] * wv[0] + (double)ev[1] * wv[1]
               + (double)ev[2] * wv[2] + (double)ev[3] * wv[3];
        }
        #pragma unroll
        for (int o = 32; o > 0; o >>= 1) s += __shfl_down(s, o);
        if (lane == 0) {
            const double z = s + (double)b_up[h];
            bex[c] = z > 0.0 ? z : 0.0;
        }
    }
    __syncthreads();

    // K = r-th largest exact band value; select strictly above K
    if (t < 128) redd[t] = -1.0;
    __syncthreads();
    if (t < nb) {
        const double v = bex[t]; int ge = 0;
        for (int j = 0; j < nb; ++j) ge += (bex[j] >= v) ? 1 : 0;
        if (ge >= r) redd[t] = v;
    }
    __syncthreads();
    for (int st = 64; st > 0; st >>= 1) {
        if (t < st) { const double o = redd[t + st]; if (o > redd[t]) redd[t] = o; }
        __syncthreads();
    }
    const double K = redd[0];

    if (t < nb && bex[t] > K) {
        const int p = atomicAdd(&nsel, 1);
        if (p < 40) { selv[p] = (float)bex[t]; seli[p] = bidx[t]; }
    }
    __syncthreads();
    const int ns = nsel < 40 ? nsel : 40;

    // x_hat[row] = sum_sel a * Wdt[h] (bf16 rows, ushort2 coalesced)
    for (int p = t; p < D_EMB / 2; p += 256) {
        float a0 = 0.f, a1 = 0.f;
        for (int c = 0; c < ns; ++c) {
            const uint32_t w2 = *(const uint32_t*)(Wdt + (size_t)seli[c] * D_EMB + 2 * p);
            a0 += selv[c] * bf2f((unsigned short)(w2 & 0xffffu));
            a1 += selv[c] * bf2f((unsigned short)(w2 >> 16));
        }
        float2 o; o.x = a0; o.y = a1;
        *(float2*)(out + (size_t)row * D_EMB + 2 * p) = o;
    }
}

// ------------------------------- launcher ------------------------------------
extern "C" void kernel_launch(void* const* d_in, const int* in_sizes, int n_in,
                              void* d_out, int out_size, void* d_ws, size_t ws_size,
                              hipStream_t stream)
{
    (void)in_sizes; (void)n_in; (void)out_size; (void)ws_size;
    const float* embs   = (const float*)d_in[0];
    const float* W_up   = (const float*)d_in[1];
    const float* b_up   = (const float*)d_in[2];
    const float* W_down = (const float*)d_in[3];
    float* out = (float*)d_out;

    char* w = (char*)d_ws;
    int*   counts = (int*)w;                                     // 64 KB
    uint2* cand8  = (uint2*)(w + (64 << 10));                    // 33.55 MB
    char*  r2     = w + (64 << 10) + (size_t)B_ROWS * CAP * 8;
    unsigned short* Abf = (unsigned short*)r2;                   // 12.58 MB
    unsigned short* Bbf = (unsigned short*)(r2 + (size_t)B_ROWS * D_EMB * 2); // 37.75 MB
    unsigned short* Wdt = (unsigned short*)r2;                   // aliases Abf/Bbf (used after GEMM)

    hipMemsetAsync(counts, 0, B_ROWS * sizeof(int), stream);
    k_cvt<<<1024, 256, 0, stream>>>(embs, Abf, B_ROWS * D_EMB / 4);
    k_cvt<<<2048, 256, 0, stream>>>(W_up, Bbf, D_HID * D_EMB / 4);

    k_gemm_cand<<<dim3(B_ROWS / 128, D_HID / 256), 256, 0, stream>>>(Abf, Bbf, b_up, counts, cand8);

    k_transpose_bf<<<dim3(D_HID / 32, D_EMB / 32), dim3(32, 8), 0, stream>>>(W_down, Wdt);

    k_select_project<<<B_ROWS, 256, 0, stream>>>(embs, W_up, b_up, Wdt, counts, cand8, out);
}

// Round 13
// 563.551 us; speedup vs baseline: 1.1048x; 1.0212x over previous
//
#include <hip/hip_runtime.h>
#include <stdint.h>

#define B_ROWS 8192
#define D_EMB  768
#define D_HID  24576
#define CAP    512
#define TAU    2.40f
#define DELTA  0.03f
#define BANDCAP 64
#define LSLOT  20

typedef float f32x4  __attribute__((ext_vector_type(4)));
typedef short s16x8  __attribute__((ext_vector_type(8)));

#define GPTR(p) ((const __attribute__((address_space(1))) void*)(const void*)(p))
#define LPTR(p) ((__attribute__((address_space(3))) void*)(void*)(p))

__device__ __forceinline__ unsigned short f2bf_rne(float f) {
    uint32_t u = __builtin_bit_cast(uint32_t, f);
    u += 0x7fffu + ((u >> 16) & 1u);
    return (unsigned short)(u >> 16);
}
__device__ __forceinline__ float bf2f(unsigned short h) {
    uint32_t u = ((uint32_t)h) << 16;
    return __builtin_bit_cast(float, u);
}

// ---------------- fp32 -> bf16 (RNE) bulk convert ---------------------------
__global__ __launch_bounds__(256) void k_cvt(const float* __restrict__ src,
                                             unsigned short* __restrict__ dst, int n4)
{
    int i = blockIdx.x * 256 + threadIdx.x;
    const int stride = gridDim.x * 256;
    for (; i < n4; i += stride) {
        float4 v = ((const float4*)src)[i];
        ushort4 o;
        o.x = f2bf_rne(v.x); o.y = f2bf_rne(v.y);
        o.z = f2bf_rne(v.z); o.w = f2bf_rne(v.w);
        ((ushort4*)dst)[i] = o;
    }
}

// ------------- transpose W_down [768][24576] -> Wdt bf16 [24576][768] -------
__global__ __launch_bounds__(256) void k_transpose_bf(const float* __restrict__ W,
                                                      unsigned short* __restrict__ WT)
{
    __shared__ float tile[32][33];
    const int bx = blockIdx.x * 32;   // along D_HID
    const int by = blockIdx.y * 32;   // along D_EMB
    const int tx = threadIdx.x, ty = threadIdx.y;
    #pragma unroll
    for (int r = ty; r < 32; r += 8)
        tile[r][tx] = W[(size_t)(by + r) * D_HID + bx + tx];
    __syncthreads();
    #pragma unroll
    for (int r = ty; r < 32; r += 8)
        WT[(size_t)(bx + r) * D_EMB + by + tx] = f2bf_rne(tile[tx][r]);
}

// -- phase 1: bf16 MFMA GEMM, 128x256 block, 64x128 wave tile + compaction ---
// Abf = embs bf16 [8192][768], Bbf = W_up bf16 [24576][768]; C = A*B^T
// K-loop = r12 structure, unrolled x2 with LITERAL buffer indices so all LDS
// addresses are loop-invariant (attacks the 22% VALUBusy issue overhead).
// 0-conflict chunk swizzle: physical chunk s of row r holds global k-chunk
// s ^ ((r>>1)&3) (pre-swizzled source, linear gload_lds dest).
// Epilogue: LDS-aggregated emission (r8-verified), unioned onto Bs staging.
__global__ __launch_bounds__(256, 2) void k_gemm_cand(
    const unsigned short* __restrict__ Abf, const unsigned short* __restrict__ Bbf,
    const float* __restrict__ bias, int* __restrict__ counts,
    uint2* __restrict__ cand8)
{
    __shared__ __align__(16) unsigned short As[2][128 * 32];   // 16 KB
    __shared__ __align__(16) unsigned short Bs[2][256 * 32];   // 32 KB
    // epilogue views aliased onto Bs (32 KB >= 21 KB needed)
    int*   lc    = (int*)&Bs[0][0];                 // [128]
    int*   lbase = lc + 128;                        // [128]
    uint2* lcand = (uint2*)(lbase + 128);           // [128][LSLOT] = 20 KB

    const int tid  = threadIdx.x;
    const int bm   = blockIdx.x * 128;
    const int bn   = blockIdx.y * 256;
    const int lane = tid & 63;
    const int wid  = tid >> 6;
    const int wr   = (wid >> 1) * 64;    // wave row offset (2 row-halves)
    const int wc   = (wid & 1) * 128;    // wave col offset (2 col-halves)

    // staging: 4 threads per row, 16B each; A: 2 issues (128 rows), B: 4 (256)
    const int srow  = tid >> 2;                      // 0..63
    const int sslot = tid & 3;                       // 16B slot
    const int kc    = sslot ^ ((srow >> 1) & 3);     // swizzled global k-chunk

    const unsigned short* ga0 = Abf + (size_t)(bm + srow) * D_EMB + kc * 8;
    const unsigned short* gb0 = Bbf + (size_t)(bn + srow) * D_EMB + kc * 8;
    const int ldst = srow * 32 + sslot * 8;          // ushort index, linear

#define STAGE(BUF, K0)                                                        \
    do {                                                                      \
        __builtin_amdgcn_global_load_lds(GPTR(ga0 + (K0)),                    \
                                         LPTR(&As[BUF][ldst]), 16, 0, 0);     \
        __builtin_amdgcn_global_load_lds(GPTR(ga0 + (size_t)64 * D_EMB + (K0)),\
                                         LPTR(&As[BUF][ldst + 64 * 32]), 16, 0, 0);\
        _Pragma("unroll")                                                     \
        for (int p_ = 0; p_ < 4; ++p_)                                        \
            __builtin_amdgcn_global_load_lds(GPTR(gb0 + (size_t)(64 * p_) * D_EMB + (K0)),\
                                             LPTR(&Bs[BUF][ldst + p_ * 64 * 32]), 16, 0, 0);\
    } while (0)

    f32x4 acc[4][8] = {};

    const int l15 = lane & 15, hi4 = lane >> 4;
    const int sw  = hi4 ^ ((l15 >> 1) & 3);          // read-side swizzle

#define BODY(BUF)                                                             \
    do {                                                                      \
        s16x8 av[4], bv[8];                                                   \
        _Pragma("unroll")                                                     \
        for (int i_ = 0; i_ < 4; ++i_)                                        \
            av[i_] = *(const s16x8*)(&As[BUF][(wr + i_ * 16 + l15) * 32 + sw * 8]);\
        _Pragma("unroll")                                                     \
        for (int j_ = 0; j_ < 8; ++j_)                                        \
            bv[j_] = *(const s16x8*)(&Bs[BUF][(wc + j_ * 16 + l15) * 32 + sw * 8]);\
        _Pragma("unroll")                                                     \
        for (int i_ = 0; i_ < 4; ++i_)                                        \
            _Pragma("unroll")                                                 \
            for (int j_ = 0; j_ < 8; ++j_)                                    \
                acc[i_][j_] = __builtin_amdgcn_mfma_f32_16x16x32_bf16(        \
                    av[i_], bv[j_], acc[i_][j_], 0, 0, 0);                    \
    } while (0)

    STAGE(0, 0);
    __syncthreads();

    // 24 K-tiles, unrolled x2: literal buffer indices -> hoisted addresses
    #pragma unroll 1
    for (int ks = 0; ks < 24; ks += 2) {
        STAGE(1, (ks + 1) * 32);
        BODY(0);
        __syncthreads();
        if (ks + 2 < 24) STAGE(0, (ks + 2) * 32);
        BODY(1);
        __syncthreads();
    }
#undef STAGE
#undef BODY

    // staging buffers now dead; re-init aliased epilogue state
    if (tid < 128) lc[tid] = 0;
    __syncthreads();

    // epilogue: C/D mapping col = lane&15, row = (lane>>4)*4 + reg  [m89]
    // pass 1: hits -> per-row LDS lists (LDS atomics)
    #pragma unroll
    for (int i = 0; i < 4; ++i) {
        const int lr0 = wr + i * 16 + hi4 * 4;       // local row base 0..127
        #pragma unroll
        for (int j = 0; j < 8; ++j) {
            const int c = bn + wc + j * 16 + l15;
            const float bb = bias[c];
            #pragma unroll
            for (int r = 0; r < 4; ++r) {
                const float z = acc[i][j][r] + bb;
                if (z > TAU) {
                    const int lr = lr0 + r;
                    const int p = atomicAdd(&lc[lr], 1);
                    if (p < LSLOT) {
                        uint2 e; e.x = (uint32_t)c; e.y = __builtin_bit_cast(uint32_t, z);
                        lcand[lr * LSLOT + p] = e;
                    }
                }
            }
        }
    }
    __syncthreads();
    // pass 2: one batched global atomic per nonzero row (parallel round-trips)
    if (tid < 128) {
        int n = lc[tid]; n = n > LSLOT ? LSLOT : n;
        lc[tid] = n;
        lbase[tid] = n ? atomicAdd(&counts[bm + tid], n) : 0;
    }
    __syncthreads();
    // pass 3: coalesced copy-out
    for (int s = tid; s < 128 * LSLOT; s += 256) {
        const int lr = s / LSLOT, k = s % LSLOT;
        if (k < lc[lr]) {
            const int pos = lbase[lr] + k;
            if (pos < CAP) cand8[(size_t)(bm + lr) * CAP + pos] = lcand[lr * LSLOT + k];
        }
    }
}

// -------- phase 2+3: two-tier select (f64 only near boundary) + down-proj ---
__global__ __launch_bounds__(256) void k_select_project(
    const float* __restrict__ embs, const float* __restrict__ W_up,
    const float* __restrict__ b_up, const unsigned short* __restrict__ Wdt,
    const int* __restrict__ counts, const uint2* __restrict__ cand8,
    float* __restrict__ out)
{
    const int row = blockIdx.x;
    const int t = threadIdx.x, lane = t & 63, wid = t >> 6;

    __shared__ __align__(16) float e_sh[D_EMB];
    __shared__ float  zv[CAP];
    __shared__ int    idx[CAP];
    __shared__ float  red[256];
    __shared__ double redd[128];
    __shared__ int    bidx[BANDCAP];
    __shared__ double bex[BANDCAP];
    __shared__ float  selv[40];
    __shared__ int    seli[40];
    __shared__ int    nband, nsel;

    for (int k = t; k < D_EMB; k += 256) e_sh[k] = embs[(size_t)row * D_EMB + k];
    int n = counts[row]; if (n > CAP) n = CAP;
    for (int c = t; c < n; c += 256) {
        uint2 e = cand8[(size_t)row * CAP + c];
        idx[c] = (int)e.x;
        zv[c]  = __builtin_bit_cast(float, e.y);
    }
    if (t == 0) { nband = 0; nsel = 0; }
    __syncthreads();

    // approximate kth = 32nd largest of z~ (rank count, ties-aware)
    float best = -1e30f;
    for (int c = t; c < n; c += 256) {
        const float v = zv[c]; int ge = 0;
        for (int j = 0; j < n; ++j) ge += (zv[j] >= v) ? 1 : 0;
        if (ge >= 32 && v > best) best = v;
    }
    red[t] = best; __syncthreads();
    for (int st = 128; st > 0; st >>= 1) {
        if (t < st) { const float o = red[t + st]; if (o > red[t]) red[t] = o; }
        __syncthreads();
    }
    const float kthA = red[0];

    // classify: confident-in (a = z~) / band (exact rescore) / out
    for (int c = t; c < n; c += 256) {
        const float v = zv[c];
        if (v > kthA + DELTA) {
            const int p = atomicAdd(&nsel, 1);
            if (p < 40) { selv[p] = v; seli[p] = idx[c]; }
        } else if (v >= kthA - DELTA) {
            const int p = atomicAdd(&nband, 1);
            if (p < BANDCAP) bidx[p] = idx[c];
        }
    }
    __syncthreads();
    const int nc = nsel < 40 ? nsel : 40;
    const int nb = nband < BANDCAP ? nband : BANDCAP;
    const int r  = 32 - nc;   // >= 1

    // exact f64 rescore of band candidates (one wave each)
    for (int c = wid; c < nb; c += 4) {
        const int h = bidx[c];
        const float* wrow = W_up + (size_t)h * D_EMB;
        double s = 0.0;
        #pragma unroll
        for (int j = 0; j < 3; ++j) {
            f32x4 wv = *(const f32x4*)(wrow + lane * 4 + j * 256);
            f32x4 ev = *(const f32x4*)(&e_sh[lane * 4 + j * 256]);
            s += (double)ev[0] * wv[0] + (double)ev[1] * wv[1]
               + (double)ev[2] * wv[2] + (double)ev[3] * wv[3];
        }
        #pragma unroll
        for (int o = 32; o > 0; o >>= 1) s += __shfl_down(s, o);
        if (lane == 0) {
            const double z = s + (double)b_up[h];
            bex[c] = z > 0.0 ? z : 0.0;
        }
    }
    __syncthreads();

    // K = r-th largest exact band value; select strictly above K
    if (t < 128) redd[t] = -1.0;
    __syncthreads();
    if (t < nb) {
        const double v = bex[t]; int ge = 0;
        for (int j = 0; j < nb; ++j) ge += (bex[j] >= v) ? 1 : 0;
        if (ge >= r) redd[t] = v;
    }
    __syncthreads();
    for (int st = 64; st > 0; st >>= 1) {
        if (t < st) { const double o = redd[t + st]; if (o > redd[t]) redd[t] = o; }
        __syncthreads();
    }
    const double K = redd[0];

    if (t < nb && bex[t] > K) {
        const int p = atomicAdd(&nsel, 1);
        if (p < 40) { selv[p] = (float)bex[t]; seli[p] = bidx[t]; }
    }
    __syncthreads();
    const int ns = nsel < 40 ? nsel : 40;

    // x_hat[row] = sum_sel a * Wdt[h]: uint2 = 4 bf16 per thread -> one
    // coalesced 1536B sweep per candidate row (192 active lanes), float4 out.
    if (t < 192) {
        float a0 = 0.f, a1 = 0.f, a2 = 0.f, a3 = 0.f;
        for (int c = 0; c < ns; ++c) {
            const uint2 w4 = *(const uint2*)(Wdt + (size_t)seli[c] * D_EMB + 4 * t);
            const float sv = selv[c];
            a0 += sv * bf2f((unsigned short)(w4.x & 0xffffu));
            a1 += sv * bf2f((unsigned short)(w4.x >> 16));
            a2 += sv * bf2f((unsigned short)(w4.y & 0xffffu));
            a3 += sv * bf2f((unsigned short)(w4.y >> 16));
        }
        f32x4 o; o[0] = a0; o[1] = a1; o[2] = a2; o[3] = a3;
        *(f32x4*)(out + (size_t)row * D_EMB + 4 * t) = o;
    }
}

// ------------------------------- launcher ------------------------------------
extern "C" void kernel_launch(void* const* d_in, const int* in_sizes, int n_in,
                              void* d_out, int out_size, void* d_ws, size_t ws_size,
                              hipStream_t stream)
{
    (void)in_sizes; (void)n_in; (void)out_size; (void)ws_size;
    const float* embs   = (const float*)d_in[0];
    const float* W_up   = (const float*)d_in[1];
    const float* b_up   = (const float*)d_in[2];
    const float* W_down = (const float*)d_in[3];
    float* out = (float*)d_out;

    char* w = (char*)d_ws;
    int*   counts = (int*)w;                                     // 64 KB
    uint2* cand8  = (uint2*)(w + (64 << 10));                    // 33.55 MB
    char*  r2     = w + (64 << 10) + (size_t)B_ROWS * CAP * 8;
    unsigned short* Abf = (unsigned short*)r2;                   // 12.58 MB
    unsigned short* Bbf = (unsigned short*)(r2 + (size_t)B_ROWS * D_EMB * 2); // 37.75 MB
    unsigned short* Wdt = (unsigned short*)r2;                   // aliases Abf/Bbf (used after GEMM)

    hipMemsetAsync(counts, 0, B_ROWS * sizeof(int), stream);
    k_cvt<<<1024, 256, 0, stream>>>(embs, Abf, B_ROWS * D_EMB / 4);
    k_cvt<<<2048, 256, 0, stream>>>(W_up, Bbf, D_HID * D_EMB / 4);

    k_gemm_cand<<<dim3(B_ROWS / 128, D_HID / 256), 256, 0, stream>>>(Abf, Bbf, b_up, counts, cand8);

    k_transpose_bf<<<dim3(D_HID / 32, D_EMB / 32), dim3(32, 8), 0, stream>>>(W_down, Wdt);

    k_select_project<<<B_ROWS, 256, 0, stream>>>(embs, W_up, b_up, Wdt, counts, cand8, out);
}